// Round 14
// baseline (208.427 us; speedup 1.0000x reference)
//
#include <hip/hip_runtime.h>
#include <hip/hip_bf16.h>
#include <stdint.h>

#define M_TOT 8192
#define N_TOT 4096
#define K_TOT 4096
#define BM 128
#define BN 128
#define BKI 64               // int8 K-tile: 64 B rows, triple-buffered
#define NTI (K_TOT / BKI)    // 64 tiles

typedef short s16x8 __attribute__((ext_vector_type(8)));
typedef float f32x4 __attribute__((ext_vector_type(4)));
typedef int   i32x4 __attribute__((ext_vector_type(4)));
typedef char  i8x16 __attribute__((ext_vector_type(16)));
typedef unsigned int u32;

// fp32 -> bf16 round-to-nearest-even (fallback path)
__device__ __forceinline__ short f2bf(float f) {
    unsigned int u = __float_as_uint(f);
    u = (u + 0x7fffu + ((u >> 16) & 1u)) >> 16;
    return (short)u;
}

__device__ __forceinline__ void async_copy16(const void* g, void* l) {
    __builtin_amdgcn_global_load_lds(
        (const __attribute__((address_space(1))) void*)g,
        (__attribute__((address_space(3))) void*)l, 16, 0, 0);
}

// ---------------- pass 1 (merged): quantize x -> int8 (per-row) + unpack W -> int8 W^T ----------------
__global__ __launch_bounds__(256)
void prep(const float* __restrict__ x, const int* __restrict__ qw,
          char* __restrict__ xq, char* __restrict__ wq,
          float* __restrict__ sxv, float* __restrict__ sumv) {
    __shared__ float rmax[4], rsum[4];
    __shared__ char tile[256 * 64];
    const int t = threadIdx.x;

    if (blockIdx.x < M_TOT) {
        // ---- per-row quantize: thread t owns 16 consecutive elems ----
        const int row = blockIdx.x;
        const float* xp = x + (size_t)row * K_TOT + t * 16;
        f32x4 f[4];
        float amax = 0.f, sum = 0.f;
        #pragma unroll
        for (int i = 0; i < 4; ++i) {
            f[i] = *(const f32x4*)(xp + i * 4);
            #pragma unroll
            for (int j = 0; j < 4; ++j) {
                amax = fmaxf(amax, fabsf(f[i][j]));
                sum += f[i][j];
            }
        }
        #pragma unroll
        for (int s = 1; s < 64; s <<= 1) {
            amax = fmaxf(amax, __shfl_xor(amax, s, 64));
            sum += __shfl_xor(sum, s, 64);
        }
        const int wv = t >> 6;
        if ((t & 63) == 0) { rmax[wv] = amax; rsum[wv] = sum; }
        __syncthreads();
        amax = fmaxf(fmaxf(rmax[0], rmax[1]), fmaxf(rmax[2], rmax[3]));
        sum  = rsum[0] + rsum[1] + rsum[2] + rsum[3];
        const float inv = amax > 0.f ? 127.0f / amax : 0.f;
        i8x16 v;
        #pragma unroll
        for (int i = 0; i < 4; ++i)
            #pragma unroll
            for (int j = 0; j < 4; ++j)
                v[i * 4 + j] = (char)(int)rintf(f[i][j] * inv);
        *(i8x16*)&xq[(size_t)row * K_TOT + t * 16] = v;
        if (t == 0) { sxv[row] = amax * (1.0f / 127.0f); sumv[row] = sum; }
    } else {
        // ---- W int4 -> int8, transposed to [OUT][IN] via LDS ----
        const int bq = blockIdx.x - M_TOT;     // 0..1023
        const int o0 = (bq & 15) * 256;
        const int kb = bq >> 4;                // 64-k block -> 32 packed rows
        const int r0 = kb * 32;
        const int o  = o0 + t;
        #pragma unroll
        for (int g = 0; g < 4; ++g) {          // granule g = 16 ks = 8 packed rows
            i8x16 v;
            #pragma unroll
            for (int p = 0; p < 8; ++p) {
                const int q = qw[(size_t)(r0 + g * 8 + p) * N_TOT + o];  // coalesced
                v[2 * p]     = (char)(q & 15);
                v[2 * p + 1] = (char)((q >> 4) & 15);
            }
            *(i8x16*)&tile[t * 64 + ((g ^ (t & 3)) << 4)] = v;
        }
        __syncthreads();
        #pragma unroll
        for (int it = 0; it < 4; ++it) {
            const int L = it * 256 + t;
            const int row = L >> 2, c = L & 3;
            *(i8x16*)&wq[(size_t)(o0 + row) * K_TOT + kb * 64 + c * 16] =
                *(const i8x16*)&tile[row * 64 + ((c ^ (row & 3)) << 4)];
        }
    }
}

// ---------------- pass 2: W4A8 int8 GEMM, BK=64 triple-buffer, counted vmcnt ----------------
// Additive per-row slot swizzle: LDS slot s' holds logical granule (s' - (row>>1)) & 3.
// Read of logical granule lk uses s' = (lk + (row>>1)) & 3  ->  2 lanes/bank-group (free).
__global__ __launch_bounds__(256, 2)
void gemm_i8(const char* __restrict__ xq, const char* __restrict__ wq,
             const float* __restrict__ sxv, const float* __restrict__ sumv,
             const float* __restrict__ scales, const float* __restrict__ zeros,
             const float* __restrict__ bias, float* __restrict__ out) {
    __shared__ __align__(16) char Sm8[49152];   // 3 x (A 8KB | B 8KB); fp32 epi buf reuse
    const int tid = threadIdx.x;
    const int n0 = blockIdx.x * BN;
    const int m0 = blockIdx.y * BM;
    const int lane = tid & 63;
    const int wv = tid >> 6;
    const int wr = wv >> 1, wc = wv & 1;
    const int lrow = lane & 15, lk = lane >> 4;

    i32x4 acc[4][4] = {};

    // stage one K-tile (A 2 loads + B 2 loads per thread) into buffer bb
    auto STAGE = [&](char* bufA, int tt) {
        const int k0 = (tt & (NTI - 1)) * BKI;
        char* bufB = bufA + 8192;
        #pragma unroll
        for (int i = 0; i < 2; ++i) {
            const int L = i * 256 + tid;
            const int row = L >> 2, c = L & 3;
            const int sk = ((c - (row >> 1)) & 3) << 4;
            async_copy16(xq + (size_t)(m0 + row) * K_TOT + k0 + sk,
                         bufA + (i * 256 + wv * 64) * 16);
        }
        #pragma unroll
        for (int i = 0; i < 2; ++i) {
            const int L = i * 256 + tid;
            const int row = L >> 2, c = L & 3;
            const int sk = ((c - (row >> 1)) & 3) << 4;
            async_copy16(wq + (size_t)(n0 + row) * K_TOT + k0 + sk,
                         bufB + (i * 256 + wv * 64) * 16);
        }
    };

    auto ITER = [&](char* bufCur, char* bufStage, int tt) {
        asm volatile("s_waitcnt vmcnt(8)" ::: "memory");   // tile tt's 4 loads landed
        __builtin_amdgcn_s_barrier();                      // visible to all waves
        char* bufB = bufCur + 8192;
        i32x4 a[4], b[4];
        #pragma unroll
        for (int mi = 0; mi < 4; ++mi) {
            const int row = wr * 64 + mi * 16 + lrow;
            const int sp = (lk + (row >> 1)) & 3;
            a[mi] = *(const i32x4*)&bufCur[row * 64 + sp * 16];
        }
        #pragma unroll
        for (int ni = 0; ni < 4; ++ni) {
            const int row = wc * 64 + ni * 16 + lrow;
            const int sp = (lk + (row >> 1)) & 3;
            b[ni] = *(const i32x4*)&bufB[row * 64 + sp * 16];
        }
        asm volatile("s_waitcnt lgkmcnt(0)" ::: "memory"); // my reads done
        __builtin_amdgcn_s_barrier();                      // all waves' reads done
        STAGE(bufStage, tt + 3);                           // refill freed buffer
        __builtin_amdgcn_s_setprio(1);
        #pragma unroll
        for (int mi = 0; mi < 4; ++mi)
            #pragma unroll
            for (int ni = 0; ni < 4; ++ni)
                acc[mi][ni] = __builtin_amdgcn_mfma_i32_16x16x64_i8(
                    a[mi], b[ni], acc[mi][ni], 0, 0, 0);
        __builtin_amdgcn_s_setprio(0);
    };

    char* const B0 = Sm8;
    char* const B1 = Sm8 + 16384;
    char* const B2 = Sm8 + 32768;

    // prologue: 3 tiles in flight (12 loads/thread)
    STAGE(B0, 0); STAGE(B1, 1); STAGE(B2, 2);

    #pragma unroll 1
    for (int t = 0; t < NTI - 1; t += 3) {      // 63 iters: t = 0..62
        ITER(B0, B0, t);
        ITER(B1, B1, t + 1);
        ITER(B2, B2, t + 2);
    }
    ITER(B0, B0, NTI - 1);                      // t = 63 (stage wraps, discarded)
    asm volatile("s_waitcnt vmcnt(0)" ::: "memory");   // drain wrapped strays

    // ---- epilogue: y = c0*sx*S1 + c1*Sx + bias; full-line stores via LDS ----
    float* fbuf = (float*)Sm8;
    float c0v[4], c1v[4], bsv[4];
    #pragma unroll
    for (int ni = 0; ni < 4; ++ni) {
        const int cg = n0 + wc * 64 + ni * 16 + lrow;
        const float c0 = scales[cg];
        c0v[ni] = c0;
        c1v[ni] = -rintf(zeros[cg] / c0) * c0;
        bsv[ni] = bias[cg];
    }
    #pragma unroll
    for (int p = 0; p < 2; ++p) {
        __syncthreads();   // prior LDS readers done
        #pragma unroll
        for (int q = 0; q < 2; ++q) {          // mi = 2p + q
            const int mi = 2 * p + q;
            const int rl = wr * 32 + q * 16 + lk * 4;
            #pragma unroll
            for (int j = 0; j < 4; ++j) {
                const int r = rl + j;
                const int gr = m0 + wr * 64 + mi * 16 + lk * 4 + j;
                const float sx = sxv[gr];
                const float Sx = sumv[gr];
                #pragma unroll
                for (int ni = 0; ni < 4; ++ni) {
                    const int col = wc * 64 + ni * 16 + lrow;
                    const float y = fmaf(c0v[ni] * sx, (float)acc[mi][ni][j],
                                         fmaf(c1v[ni], Sx, bsv[ni]));
                    fbuf[r * 128 + (col ^ (((r >> 2) & 1) << 4))] = y;
                }
            }
        }
        __syncthreads();
        #pragma unroll
        for (int rd = 0; rd < 8; ++rd) {
            const int L = rd * 256 + tid;
            const int r = L >> 5;
            const int c4 = (L & 31) * 4;
            const float4 v = *(const float4*)&fbuf[r * 128 + (c4 ^ (((r >> 2) & 1) << 4))];
            const int grow = m0 + (r >> 5) * 64 + p * 32 + (r & 31);
            *(float4*)&out[(size_t)grow * N_TOT + n0 + c4] = v;
        }
    }
}

// ---------------- fallback: fused bf16 kernel (small ws) ----------------
__global__ __launch_bounds__(256, 2)
void qlin_fused(const float* __restrict__ x,
                const int* __restrict__ qw,
                const float* __restrict__ scales,
                const float* __restrict__ zeros,
                const float* __restrict__ bias,
                float* __restrict__ out) {
    __shared__ short As[128 * 64];
    __shared__ short Bs[128 * 64];

    const int tid = threadIdx.x;
    const int n0 = blockIdx.x * 128;
    const int m0 = blockIdx.y * 128;

    const int a_kg   = tid & 7;
    const int a_row0 = tid >> 3;
    const int b_oloc = tid & 127;
    const int b_rg0  = tid >> 7;

    const int ocol = n0 + b_oloc;
    const float c0 = scales[ocol];
    const float c1 = -rintf(zeros[ocol] / c0) * c0;

    const int lane = tid & 63;
    const int wv   = tid >> 6;
    const int wr   = wv >> 1;
    const int wc   = wv & 1;
    const int lrow = lane & 15;
    const int lk   = lane >> 4;

    f32x4 acc[4][4] = {};

    for (int kt = 0; kt < K_TOT / 64; ++kt) {
        const int k0 = kt * 64;
        {
            const float* srcb = x + (size_t)(m0)*K_TOT + k0 + a_kg * 8;
            #pragma unroll
            for (int i = 0; i < 4; ++i) {
                const int row = a_row0 + 32 * i;
                const float4 f0 = *(const float4*)(srcb + (size_t)row * K_TOT);
                const float4 f1 = *(const float4*)(srcb + (size_t)row * K_TOT + 4);
                s16x8 v;
                v[0] = f2bf(f0.x); v[1] = f2bf(f0.y); v[2] = f2bf(f0.z); v[3] = f2bf(f0.w);
                v[4] = f2bf(f1.x); v[5] = f2bf(f1.y); v[6] = f2bf(f1.z); v[7] = f2bf(f1.w);
                *(s16x8*)&As[row * 64 + ((a_kg ^ (row & 7)) << 3)] = v;
            }
        }
        {
            const int rbase = k0 >> 1;
            #pragma unroll
            for (int i = 0; i < 4; ++i) {
                const int rg = b_rg0 + 2 * i;
                const int* qp = qw + (size_t)(rbase + rg * 4) * N_TOT + ocol;
                s16x8 v;
                #pragma unroll
                for (int rr = 0; rr < 4; ++rr) {
                    const int q = qp[(size_t)rr * N_TOT];
                    v[2 * rr]     = f2bf(fmaf((float)(q & 15), c0, c1));
                    v[2 * rr + 1] = f2bf(fmaf((float)((q >> 4) & 15), c0, c1));
                }
                *(s16x8*)&Bs[b_oloc * 64 + ((rg ^ (b_oloc & 7)) << 3)] = v;
            }
        }
        __syncthreads();
        #pragma unroll
        for (int ks = 0; ks < 2; ++ks) {
            const int slot = ks * 4 + lk;
            s16x8 a[4], b[4];
            #pragma unroll
            for (int mi = 0; mi < 4; ++mi) {
                const int row = wr * 64 + mi * 16 + lrow;
                a[mi] = *(const s16x8*)&As[row * 64 + ((slot ^ (row & 7)) << 3)];
            }
            #pragma unroll
            for (int ni = 0; ni < 4; ++ni) {
                const int row = wc * 64 + ni * 16 + lrow;
                b[ni] = *(const s16x8*)&Bs[row * 64 + ((slot ^ (row & 7)) << 3)];
            }
            #pragma unroll
            for (int mi = 0; mi < 4; ++mi)
                #pragma unroll
                for (int ni = 0; ni < 4; ++ni)
                    acc[mi][ni] = __builtin_amdgcn_mfma_f32_16x16x32_bf16(
                        a[mi], b[ni], acc[mi][ni], 0, 0, 0);
        }
        __syncthreads();
    }

    #pragma unroll
    for (int mi = 0; mi < 4; ++mi) {
        const int rg = m0 + wr * 64 + mi * 16 + lk * 4;
        #pragma unroll
        for (int ni = 0; ni < 4; ++ni) {
            const int cg = n0 + wc * 64 + ni * 16 + lrow;
            const float bs = bias[cg];
            #pragma unroll
            for (int j = 0; j < 4; ++j)
                out[(size_t)(rg + j) * N_TOT + cg] = acc[mi][ni][j] + bs;
        }
    }
}

extern "C" void kernel_launch(void* const* d_in, const int* in_sizes, int n_in,
                              void* d_out, int out_size, void* d_ws, size_t ws_size,
                              hipStream_t stream) {
    const float* x      = (const float*)d_in[0];
    const int*   qw     = (const int*)d_in[1];
    const float* scales = (const float*)d_in[2];
    const float* zeros  = (const float*)d_in[3];
    const float* bias   = (const float*)d_in[4];
    float* out = (float*)d_out;

    const size_t XQ_BYTES = (size_t)M_TOT * K_TOT;        // 32 MiB
    const size_t WQ_BYTES = (size_t)N_TOT * K_TOT;        // 16 MiB
    const size_t SX_BYTES = (size_t)M_TOT * 4;
    const size_t NEED = XQ_BYTES + WQ_BYTES + 2 * SX_BYTES;

    if (ws_size >= NEED) {
        char*  xq   = (char*)d_ws;
        char*  wqt  = (char*)d_ws + XQ_BYTES;
        float* sxv  = (float*)((char*)d_ws + XQ_BYTES + WQ_BYTES);
        float* sumv = sxv + M_TOT;

        hipLaunchKernelGGL(prep, dim3(M_TOT + 1024), dim3(256), 0, stream,
                           x, qw, xq, wqt, sxv, sumv);
        hipLaunchKernelGGL(gemm_i8, dim3(N_TOT / BN, M_TOT / BM), dim3(256), 0, stream,
                           xq, wqt, sxv, sumv, scales, zeros, bias, out);
    } else {
        hipLaunchKernelGGL(qlin_fused, dim3(N_TOT / 128, M_TOT / 128), dim3(256), 0, stream,
                           x, qw, scales, zeros, bias, out);
    }
}

// Round 15
// 173.731 us; speedup vs baseline: 1.1997x; 1.1997x over previous
//
#include <hip/hip_runtime.h>
#include <hip/hip_bf16.h>
#include <stdint.h>

#define M_TOT 8192
#define N_TOT 4096
#define K_TOT 4096
#define BM 128
#define BN 128
#define BKI 128              // int8 K-tile: 128 B rows -> conflict-free granule swizzle
#define NTI (K_TOT / BKI)    // 32 tiles

typedef short s16x8 __attribute__((ext_vector_type(8)));
typedef float f32x4 __attribute__((ext_vector_type(4)));
typedef int   i32x4 __attribute__((ext_vector_type(4)));
typedef char  i8x16 __attribute__((ext_vector_type(16)));
typedef unsigned int u32;

// fp32 -> bf16 round-to-nearest-even (fallback path)
__device__ __forceinline__ short f2bf(float f) {
    unsigned int u = __float_as_uint(f);
    u = (u + 0x7fffu + ((u >> 16) & 1u)) >> 16;
    return (short)u;
}

__device__ __forceinline__ void async_copy16(const void* g, void* l) {
    __builtin_amdgcn_global_load_lds(
        (const __attribute__((address_space(1))) void*)g,
        (__attribute__((address_space(3))) void*)l, 16, 0, 0);
}

// ---------------- pass 1 (merged): quantize x -> int8 (per-row) + unpack W -> int8 W^T ----------------
__global__ __launch_bounds__(256)
void prep(const float* __restrict__ x, const int* __restrict__ qw,
          char* __restrict__ xq, char* __restrict__ wq,
          float* __restrict__ sxv, float* __restrict__ sumv) {
    __shared__ float rmax[4], rsum[4];
    __shared__ char tile[256 * 64];
    const int t = threadIdx.x;

    if (blockIdx.x < M_TOT) {
        // ---- per-row quantize: thread t owns 16 consecutive elems ----
        const int row = blockIdx.x;
        const float* xp = x + (size_t)row * K_TOT + t * 16;
        f32x4 f[4];
        float amax = 0.f, sum = 0.f;
        #pragma unroll
        for (int i = 0; i < 4; ++i) {
            f[i] = *(const f32x4*)(xp + i * 4);
            #pragma unroll
            for (int j = 0; j < 4; ++j) {
                amax = fmaxf(amax, fabsf(f[i][j]));
                sum += f[i][j];
            }
        }
        #pragma unroll
        for (int s = 1; s < 64; s <<= 1) {
            amax = fmaxf(amax, __shfl_xor(amax, s, 64));
            sum += __shfl_xor(sum, s, 64);
        }
        const int wv = t >> 6;
        if ((t & 63) == 0) { rmax[wv] = amax; rsum[wv] = sum; }
        __syncthreads();
        amax = fmaxf(fmaxf(rmax[0], rmax[1]), fmaxf(rmax[2], rmax[3]));
        sum  = rsum[0] + rsum[1] + rsum[2] + rsum[3];
        const float inv = amax > 0.f ? 127.0f / amax : 0.f;
        i8x16 v;
        #pragma unroll
        for (int i = 0; i < 4; ++i)
            #pragma unroll
            for (int j = 0; j < 4; ++j)
                v[i * 4 + j] = (char)(int)rintf(f[i][j] * inv);
        *(i8x16*)&xq[(size_t)row * K_TOT + t * 16] = v;
        if (t == 0) { sxv[row] = amax * (1.0f / 127.0f); sumv[row] = sum; }
    } else {
        // ---- W int4 -> int8, transposed to [OUT][IN] via LDS ----
        const int bq = blockIdx.x - M_TOT;     // 0..1023
        const int o0 = (bq & 15) * 256;
        const int kb = bq >> 4;                // 64-k block -> 32 packed rows
        const int r0 = kb * 32;
        const int o  = o0 + t;
        #pragma unroll
        for (int g = 0; g < 4; ++g) {          // granule g = 16 ks = 8 packed rows
            i8x16 v;
            #pragma unroll
            for (int p = 0; p < 8; ++p) {
                const int q = qw[(size_t)(r0 + g * 8 + p) * N_TOT + o];  // coalesced
                v[2 * p]     = (char)(q & 15);
                v[2 * p + 1] = (char)((q >> 4) & 15);
            }
            *(i8x16*)&tile[t * 64 + ((g ^ (t & 3)) << 4)] = v;
        }
        __syncthreads();
        #pragma unroll
        for (int it = 0; it < 4; ++it) {
            const int L = it * 256 + t;
            const int row = L >> 2, c = L & 3;
            *(i8x16*)&wq[(size_t)(o0 + row) * K_TOT + kb * 64 + c * 16] =
                *(const i8x16*)&tile[row * 64 + ((c ^ (row & 3)) << 4)];
        }
    }
}

// ---------------- pass 2: W4A8 int8 GEMM (r7 structure, BK=128 int8) ----------------
__global__ __launch_bounds__(256, 2)
void gemm_i8(const char* __restrict__ xq, const char* __restrict__ wq,
             const float* __restrict__ sxv, const float* __restrict__ sumv,
             const float* __restrict__ scales, const float* __restrict__ zeros,
             const float* __restrict__ bias, float* __restrict__ out) {
    __shared__ __align__(16) char Sm8[32768];   // As | Bs (16 KB each); reused as fp32 epilogue buf
    char* As = Sm8;
    char* Bs = Sm8 + 16384;

    const int tid = threadIdx.x;
    const int n0 = blockIdx.x * BN;
    const int m0 = blockIdx.y * BM;
    const int lane = tid & 63;
    const int wv = tid >> 6;
    const int wr = wv >> 1, wc = wv & 1;
    const int lrow = lane & 15, lk = lane >> 4;

    i32x4 acc[4][4] = {};

    for (int kt = 0; kt < NTI; ++kt) {
        const int k0 = kt * BKI;
        // stage A: 1024 granules of 16B (128 rows x 8); LDS (row,c) <- global (row, c^(row&7))
        #pragma unroll
        for (int i = 0; i < 4; ++i) {
            const int g = i * 256 + wv * 64 + lane;
            const int row = g >> 3, c = g & 7;
            async_copy16(xq + (size_t)(m0 + row) * K_TOT + k0 + ((c ^ (row & 7)) << 4),
                         &As[(i * 256 + wv * 64) * 16]);
        }
        #pragma unroll
        for (int i = 0; i < 4; ++i) {
            const int g = i * 256 + wv * 64 + lane;
            const int row = g >> 3, c = g & 7;
            async_copy16(wq + (size_t)(n0 + row) * K_TOT + k0 + ((c ^ (row & 7)) << 4),
                         &Bs[(i * 256 + wv * 64) * 16]);
        }
        __syncthreads();   // vmcnt(0) drain + barrier

        #pragma unroll
        for (int ks = 0; ks < 2; ++ks) {
            const int slot = ks * 4 + lk;      // granule (16 ks) within 128-B row
            i32x4 a[4], b[4];
            #pragma unroll
            for (int mi = 0; mi < 4; ++mi) {
                const int row = wr * 64 + mi * 16 + lrow;
                a[mi] = *(const i32x4*)&As[row * 128 + ((slot ^ (row & 7)) << 4)];
            }
            #pragma unroll
            for (int ni = 0; ni < 4; ++ni) {
                const int row = wc * 64 + ni * 16 + lrow;
                b[ni] = *(const i32x4*)&Bs[row * 128 + ((slot ^ (row & 7)) << 4)];
            }
            #pragma unroll
            for (int mi = 0; mi < 4; ++mi)
                #pragma unroll
                for (int ni = 0; ni < 4; ++ni)
                    acc[mi][ni] = __builtin_amdgcn_mfma_i32_16x16x64_i8(
                        a[mi], b[ni], acc[mi][ni], 0, 0, 0);
        }
        __syncthreads();
    }

    // ---- epilogue: y = c0*sx*S1 + c1*Sx + bias; full-line stores via LDS ----
    float* fbuf = (float*)Sm8;
    float c0v[4], c1v[4], bsv[4];
    #pragma unroll
    for (int ni = 0; ni < 4; ++ni) {
        const int cg = n0 + wc * 64 + ni * 16 + lrow;
        const float c0 = scales[cg];
        c0v[ni] = c0;
        c1v[ni] = -rintf(zeros[cg] / c0) * c0;
        bsv[ni] = bias[cg];
    }
    #pragma unroll
    for (int p = 0; p < 2; ++p) {
        __syncthreads();   // prior LDS readers done
        #pragma unroll
        for (int q = 0; q < 2; ++q) {          // mi = 2p + q
            const int mi = 2 * p + q;
            const int rl = wr * 32 + q * 16 + lk * 4;
            #pragma unroll
            for (int j = 0; j < 4; ++j) {
                const int r = rl + j;
                const int gr = m0 + wr * 64 + mi * 16 + lk * 4 + j;
                const float sx = sxv[gr];
                const float Sx = sumv[gr];
                #pragma unroll
                for (int ni = 0; ni < 4; ++ni) {
                    const int col = wc * 64 + ni * 16 + lrow;
                    const float y = fmaf(c0v[ni] * sx, (float)acc[mi][ni][j],
                                         fmaf(c1v[ni], Sx, bsv[ni]));
                    fbuf[r * 128 + (col ^ (((r >> 2) & 1) << 4))] = y;
                }
            }
        }
        __syncthreads();
        #pragma unroll
        for (int rd = 0; rd < 8; ++rd) {
            const int L = rd * 256 + tid;
            const int r = L >> 5;
            const int c4 = (L & 31) * 4;
            const float4 v = *(const float4*)&fbuf[r * 128 + (c4 ^ (((r >> 2) & 1) << 4))];
            const int grow = m0 + (r >> 5) * 64 + p * 32 + (r & 31);
            *(float4*)&out[(size_t)grow * N_TOT + n0 + c4] = v;
        }
    }
}

// ---------------- fallback: fused bf16 kernel (small ws) ----------------
__global__ __launch_bounds__(256, 2)
void qlin_fused(const float* __restrict__ x,
                const int* __restrict__ qw,
                const float* __restrict__ scales,
                const float* __restrict__ zeros,
                const float* __restrict__ bias,
                float* __restrict__ out) {
    __shared__ short As[128 * 64];
    __shared__ short Bs[128 * 64];

    const int tid = threadIdx.x;
    const int n0 = blockIdx.x * 128;
    const int m0 = blockIdx.y * 128;

    const int a_kg   = tid & 7;
    const int a_row0 = tid >> 3;
    const int b_oloc = tid & 127;
    const int b_rg0  = tid >> 7;

    const int ocol = n0 + b_oloc;
    const float c0 = scales[ocol];
    const float c1 = -rintf(zeros[ocol] / c0) * c0;

    const int lane = tid & 63;
    const int wv   = tid >> 6;
    const int wr   = wv >> 1;
    const int wc   = wv & 1;
    const int lrow = lane & 15;
    const int lk   = lane >> 4;

    f32x4 acc[4][4] = {};

    for (int kt = 0; kt < K_TOT / 64; ++kt) {
        const int k0 = kt * 64;
        {
            const float* srcb = x + (size_t)(m0)*K_TOT + k0 + a_kg * 8;
            #pragma unroll
            for (int i = 0; i < 4; ++i) {
                const int row = a_row0 + 32 * i;
                const float4 f0 = *(const float4*)(srcb + (size_t)row * K_TOT);
                const float4 f1 = *(const float4*)(srcb + (size_t)row * K_TOT + 4);
                s16x8 v;
                v[0] = f2bf(f0.x); v[1] = f2bf(f0.y); v[2] = f2bf(f0.z); v[3] = f2bf(f0.w);
                v[4] = f2bf(f1.x); v[5] = f2bf(f1.y); v[6] = f2bf(f1.z); v[7] = f2bf(f1.w);
                *(s16x8*)&As[row * 64 + ((a_kg ^ (row & 7)) << 3)] = v;
            }
        }
        {
            const int rbase = k0 >> 1;
            #pragma unroll
            for (int i = 0; i < 4; ++i) {
                const int rg = b_rg0 + 2 * i;
                const int* qp = qw + (size_t)(rbase + rg * 4) * N_TOT + ocol;
                s16x8 v;
                #pragma unroll
                for (int rr = 0; rr < 4; ++rr) {
                    const int q = qp[(size_t)rr * N_TOT];
                    v[2 * rr]     = f2bf(fmaf((float)(q & 15), c0, c1));
                    v[2 * rr + 1] = f2bf(fmaf((float)((q >> 4) & 15), c0, c1));
                }
                *(s16x8*)&Bs[b_oloc * 64 + ((rg ^ (b_oloc & 7)) << 3)] = v;
            }
        }
        __syncthreads();
        #pragma unroll
        for (int ks = 0; ks < 2; ++ks) {
            const int slot = ks * 4 + lk;
            s16x8 a[4], b[4];
            #pragma unroll
            for (int mi = 0; mi < 4; ++mi) {
                const int row = wr * 64 + mi * 16 + lrow;
                a[mi] = *(const s16x8*)&As[row * 64 + ((slot ^ (row & 7)) << 3)];
            }
            #pragma unroll
            for (int ni = 0; ni < 4; ++ni) {
                const int row = wc * 64 + ni * 16 + lrow;
                b[ni] = *(const s16x8*)&Bs[row * 64 + ((slot ^ (row & 7)) << 3)];
            }
            #pragma unroll
            for (int mi = 0; mi < 4; ++mi)
                #pragma unroll
                for (int ni = 0; ni < 4; ++ni)
                    acc[mi][ni] = __builtin_amdgcn_mfma_f32_16x16x32_bf16(
                        a[mi], b[ni], acc[mi][ni], 0, 0, 0);
        }
        __syncthreads();
    }

    #pragma unroll
    for (int mi = 0; mi < 4; ++mi) {
        const int rg = m0 + wr * 64 + mi * 16 + lk * 4;
        #pragma unroll
        for (int ni = 0; ni < 4; ++ni) {
            const int cg = n0 + wc * 64 + ni * 16 + lrow;
            const float bs = bias[cg];
            #pragma unroll
            for (int j = 0; j < 4; ++j)
                out[(size_t)(rg + j) * N_TOT + cg] = acc[mi][ni][j] + bs;
        }
    }
}

extern "C" void kernel_launch(void* const* d_in, const int* in_sizes, int n_in,
                              void* d_out, int out_size, void* d_ws, size_t ws_size,
                              hipStream_t stream) {
    const float* x      = (const float*)d_in[0];
    const int*   qw     = (const int*)d_in[1];
    const float* scales = (const float*)d_in[2];
    const float* zeros  = (const float*)d_in[3];
    const float* bias   = (const float*)d_in[4];
    float* out = (float*)d_out;

    const size_t XQ_BYTES = (size_t)M_TOT * K_TOT;        // 32 MiB
    const size_t WQ_BYTES = (size_t)N_TOT * K_TOT;        // 16 MiB
    const size_t SX_BYTES = (size_t)M_TOT * 4;
    const size_t NEED = XQ_BYTES + WQ_BYTES + 2 * SX_BYTES;

    if (ws_size >= NEED) {
        char*  xq   = (char*)d_ws;
        char*  wqt  = (char*)d_ws + XQ_BYTES;
        float* sxv  = (float*)((char*)d_ws + XQ_BYTES + WQ_BYTES);
        float* sumv = sxv + M_TOT;

        hipLaunchKernelGGL(prep, dim3(M_TOT + 1024), dim3(256), 0, stream,
                           x, qw, xq, wqt, sxv, sumv);
        hipLaunchKernelGGL(gemm_i8, dim3(N_TOT / BN, M_TOT / BM), dim3(256), 0, stream,
                           xq, wqt, sxv, sumv, scales, zeros, bias, out);
    } else {
        hipLaunchKernelGGL(qlin_fused, dim3(N_TOT / 128, M_TOT / 128), dim3(256), 0, stream,
                           x, qw, scales, zeros, bias, out);
    }
}

// Round 16
// 172.114 us; speedup vs baseline: 1.2110x; 1.0094x over previous
//
#include <hip/hip_runtime.h>
#include <hip/hip_bf16.h>
#include <stdint.h>

#define M_TOT 8192
#define N_TOT 4096
#define K_TOT 4096
#define BM 256
#define BN 256
#define BKI 128              // int8 K-tile: 128-B rows -> r7's conflict-free granule swizzle
#define NTI (K_TOT / BKI)    // 32 tiles

typedef short s16x8 __attribute__((ext_vector_type(8)));
typedef float f32x4 __attribute__((ext_vector_type(4)));
typedef int   i32x4 __attribute__((ext_vector_type(4)));
typedef char  i8x16 __attribute__((ext_vector_type(16)));
typedef unsigned int u32;

// fp32 -> bf16 round-to-nearest-even (fallback path)
__device__ __forceinline__ short f2bf(float f) {
    unsigned int u = __float_as_uint(f);
    u = (u + 0x7fffu + ((u >> 16) & 1u)) >> 16;
    return (short)u;
}

__device__ __forceinline__ void async_copy16(const void* g, void* l) {
    __builtin_amdgcn_global_load_lds(
        (const __attribute__((address_space(1))) void*)g,
        (__attribute__((address_space(3))) void*)l, 16, 0, 0);
}

// ---------------- pass 1 (merged): quantize x -> int8 (per-row) + unpack W -> int8 W^T ----------------
__global__ __launch_bounds__(256)
void prep(const float* __restrict__ x, const int* __restrict__ qw,
          char* __restrict__ xq, char* __restrict__ wq,
          float* __restrict__ sxv, float* __restrict__ sumv) {
    __shared__ float rmax[4], rsum[4];
    __shared__ char tile[256 * 64];
    const int t = threadIdx.x;

    if (blockIdx.x < M_TOT) {
        const int row = blockIdx.x;
        const float* xp = x + (size_t)row * K_TOT + t * 16;
        f32x4 f[4];
        float amax = 0.f, sum = 0.f;
        #pragma unroll
        for (int i = 0; i < 4; ++i) {
            f[i] = *(const f32x4*)(xp + i * 4);
            #pragma unroll
            for (int j = 0; j < 4; ++j) {
                amax = fmaxf(amax, fabsf(f[i][j]));
                sum += f[i][j];
            }
        }
        #pragma unroll
        for (int s = 1; s < 64; s <<= 1) {
            amax = fmaxf(amax, __shfl_xor(amax, s, 64));
            sum += __shfl_xor(sum, s, 64);
        }
        const int wv = t >> 6;
        if ((t & 63) == 0) { rmax[wv] = amax; rsum[wv] = sum; }
        __syncthreads();
        amax = fmaxf(fmaxf(rmax[0], rmax[1]), fmaxf(rmax[2], rmax[3]));
        sum  = rsum[0] + rsum[1] + rsum[2] + rsum[3];
        const float inv = amax > 0.f ? 127.0f / amax : 0.f;
        i8x16 v;
        #pragma unroll
        for (int i = 0; i < 4; ++i)
            #pragma unroll
            for (int j = 0; j < 4; ++j)
                v[i * 4 + j] = (char)(int)rintf(f[i][j] * inv);
        *(i8x16*)&xq[(size_t)row * K_TOT + t * 16] = v;
        if (t == 0) { sxv[row] = amax * (1.0f / 127.0f); sumv[row] = sum; }
    } else {
        const int bq = blockIdx.x - M_TOT;     // 0..1023
        const int o0 = (bq & 15) * 256;
        const int kb = bq >> 4;
        const int r0 = kb * 32;
        const int o  = o0 + t;
        #pragma unroll
        for (int g = 0; g < 4; ++g) {
            i8x16 v;
            #pragma unroll
            for (int p = 0; p < 8; ++p) {
                const int q = qw[(size_t)(r0 + g * 8 + p) * N_TOT + o];
                v[2 * p]     = (char)(q & 15);
                v[2 * p + 1] = (char)((q >> 4) & 15);
            }
            *(i8x16*)&tile[t * 64 + ((g ^ (t & 3)) << 4)] = v;
        }
        __syncthreads();
        #pragma unroll
        for (int it = 0; it < 4; ++it) {
            const int L = it * 256 + t;
            const int row = L >> 2, c = L & 3;
            *(i8x16*)&wq[(size_t)(o0 + row) * K_TOT + kb * 64 + c * 16] =
                *(const i8x16*)&tile[row * 64 + ((c ^ (row & 3)) << 4)];
        }
    }
}

// ---------------- pass 2: W4A8 int8 GEMM, 256^2 8-phase snake, counted vmcnt(6) ----------------
__global__ __launch_bounds__(512, 2)
void gemm_i8(const char* __restrict__ xq, const char* __restrict__ wq,
             const float* __restrict__ sxv, const float* __restrict__ sumv,
             const float* __restrict__ scales, const float* __restrict__ zeros,
             const float* __restrict__ bias, float* __restrict__ out) {
    __shared__ __align__(16) char Sm8[131072];  // As[2] 32KB each | Bs[2] 32KB each
    char* const Asb[2] = { Sm8,          Sm8 + 32768 };
    char* const Bsb[2] = { Sm8 + 65536,  Sm8 + 98304 };

    const int tid  = threadIdx.x;
    const int n0   = blockIdx.x * BN;           // n fastest: plain grid (FETCH-proven order)
    const int m0   = blockIdx.y * BM;
    const int lane = tid & 63;
    const int wid  = tid >> 6;                  // 0..7
    const int wr   = wid >> 2;                  // 0..1 (128-row band)
    const int wc   = wid & 3;                   // 0..3 (64-col band)
    const int lrow = lane & 15;
    const int lk   = lane >> 4;
    const int gb0  = tid & 448;                 // wave-aligned tid base

    i32x4 acc[8][4] = {};
    i32x4 afr[4][2], bfr[2][2];

    // stage A half-chunk: rows {r : bit6(r)==half}; 2 x global_load_lds_dwordx4 / thread
    auto stageA = [&](int bb, int kt, int half) {
        const int k0 = (kt & (NTI - 1)) * BKI;
        #pragma unroll
        for (int j = 0; j < 2; ++j) {
            const int g  = j * 512 + tid;
            const int R  = ((g >> 3) & 63) + ((g >> 9) & 1) * 128 + half * 64;
            const int c  = g & 7;
            const int gb = j * 512 + gb0;
            const int Rb = ((gb >> 3) & 63) + ((gb >> 9) & 1) * 128 + half * 64;
            async_copy16(xq + (size_t)(m0 + R) * K_TOT + k0 + ((c ^ (R & 7)) << 4),
                         &Asb[bb][Rb * 128]);
        }
    };
    // stage B half-chunk: cols {c : bit5(c)==half}
    auto stageB = [&](int bb, int kt, int half) {
        const int k0 = (kt & (NTI - 1)) * BKI;
        #pragma unroll
        for (int j = 0; j < 2; ++j) {
            const int g  = j * 512 + tid;
            const int R  = ((g >> 3) & 31) + ((g >> 8) & 3) * 64 + half * 32;
            const int c  = g & 7;
            const int gb = j * 512 + gb0;
            const int Rb = ((gb >> 3) & 31) + ((gb >> 8) & 3) * 64 + half * 32;
            async_copy16(wq + (size_t)(n0 + R) * K_TOT + k0 + ((c ^ (R & 7)) << 4),
                         &Bsb[bb][Rb * 128]);
        }
    };

#define READ_A(BUF, MH)                                                          \
    _Pragma("unroll")                                                            \
    for (int mi = 0; mi < 4; ++mi) {                                             \
        const int row = wr * 128 + (MH) * 64 + mi * 16 + lrow;                   \
        _Pragma("unroll")                                                        \
        for (int ks = 0; ks < 2; ++ks) {                                         \
            const int slot = ks * 4 + lk;                                        \
            afr[mi][ks] = *(const i32x4*)&Asb[BUF][row * 128 + ((slot ^ (row & 7)) << 4)]; \
        }                                                                        \
    }

#define READ_B(BUF, NH)                                                          \
    _Pragma("unroll")                                                            \
    for (int ni = 0; ni < 2; ++ni) {                                             \
        const int row = wc * 64 + (NH) * 32 + ni * 16 + lrow;                    \
        _Pragma("unroll")                                                        \
        for (int ks = 0; ks < 2; ++ks) {                                         \
            const int slot = ks * 4 + lk;                                        \
            bfr[ni][ks] = *(const i32x4*)&Bsb[BUF][row * 128 + ((slot ^ (row & 7)) << 4)]; \
        }                                                                        \
    }

#define PHASE(BUF, MH, NH, RA, RB, STAGE_STMT, VM)                               \
    {                                                                            \
        if (RA) { READ_A(BUF, MH); }                                             \
        if (RB) { READ_B(BUF, NH); }                                             \
        STAGE_STMT;                                                              \
        if (VM) asm volatile("s_waitcnt vmcnt(6)" ::: "memory");                 \
        __builtin_amdgcn_s_barrier();                                            \
        asm volatile("s_waitcnt lgkmcnt(0)" ::: "memory");                       \
        __builtin_amdgcn_s_setprio(1);                                           \
        _Pragma("unroll")                                                        \
        for (int ks = 0; ks < 2; ++ks)                                           \
            _Pragma("unroll")                                                    \
            for (int mi = 0; mi < 4; ++mi)                                       \
                _Pragma("unroll")                                                \
                for (int ni = 0; ni < 2; ++ni)                                   \
                    acc[(MH) * 4 + mi][(NH) * 2 + ni] =                          \
                        __builtin_amdgcn_mfma_i32_16x16x64_i8(                   \
                            afr[mi][ks], bfr[ni][ks],                            \
                            acc[(MH) * 4 + mi][(NH) * 2 + ni], 0, 0, 0);         \
        __builtin_amdgcn_s_setprio(0);                                           \
        __builtin_amdgcn_s_barrier();                                            \
    }

    // prologue: tile0 {A h0, B h0, A h1, B h1} + tile1 {A h0, B h1, A h1} = 14 loads
    stageA(0, 0, 0); stageB(0, 0, 0); stageA(0, 0, 1); stageB(0, 0, 1);
    stageA(1, 1, 0); stageB(1, 1, 1); stageA(1, 1, 1);
    asm volatile("s_waitcnt vmcnt(6)" ::: "memory");   // tile0 fully landed
    __builtin_amdgcn_s_barrier();

    // snake quads (0,0)->(0,1)->(1,1)->(1,0); WAR/RAW audit in round notes
    for (int i = 0; i < NTI / 2; ++i) {
        const int t = 2 * i;
        PHASE(0, 0, 0, 1, 1, stageB(1, t + 1, 0), 0);
        PHASE(0, 0, 1, 0, 1, stageA(0, t + 2, 0), 0);
        PHASE(0, 1, 1, 1, 0, stageB(0, t + 2, 1), 0);
        PHASE(0, 1, 0, 0, 1, stageA(0, t + 2, 1), 1);   // vmcnt(6): tile t+1 complete
        PHASE(1, 0, 0, 1, 1, stageB(0, t + 2, 0), 0);
        PHASE(1, 0, 1, 0, 1, stageA(1, t + 3, 0), 0);
        PHASE(1, 1, 1, 1, 0, stageB(1, t + 3, 1), 0);
        PHASE(1, 1, 0, 0, 1, stageA(1, t + 3, 1), 1);   // vmcnt(6): tile t+2 complete
    }
    asm volatile("s_waitcnt vmcnt(0)" ::: "memory");    // drain wrapped strays

    // ---- epilogue: y = c0*sx*S1 + c1*Sx + bias; 4 passes of 64x256 fp32 via LDS ----
    float* fbuf = (float*)Sm8;                          // 64 x 256 fp32 = 64 KB
    float c0v[4], c1v[4], bsv[4];
    #pragma unroll
    for (int ni = 0; ni < 4; ++ni) {
        const int cg = n0 + wc * 64 + ni * 16 + lrow;
        const float c0 = scales[cg];
        c0v[ni] = c0;
        c1v[ni] = -rintf(zeros[cg] / c0) * c0;
        bsv[ni] = bias[cg];
    }
    #pragma unroll
    for (int p = 0; p < 4; ++p) {                       // rows p*64 .. p*64+63
        __syncthreads();
        if (wr == (p >> 1)) {
            #pragma unroll
            for (int mq = 0; mq < 4; ++mq) {
                const int mi8 = (p & 1) * 4 + mq;
                #pragma unroll
                for (int j = 0; j < 4; ++j) {
                    const int rl = mq * 16 + lk * 4 + j;         // 0..63
                    const int gr = m0 + p * 64 + rl;
                    const float sx = sxv[gr];
                    const float Sx = sumv[gr];
                    #pragma unroll
                    for (int ni = 0; ni < 4; ++ni) {
                        const int cf = wc * 64 + ni * 16 + lrow; // 0..255
                        const float y = fmaf(c0v[ni] * sx, (float)acc[mi8][ni][j],
                                             fmaf(c1v[ni], Sx, bsv[ni]));
                        fbuf[rl * 256 + (cf ^ (((rl >> 2) & 1) << 4))] = y;
                    }
                }
            }
        }
        __syncthreads();
        #pragma unroll
        for (int rd = 0; rd < 8; ++rd) {                // 64 rows x 64 float4 / 512 thr
            const int L = rd * 512 + tid;
            const int r = L >> 6;
            const int c4 = (L & 63) * 4;
            const float4 v = *(const float4*)&fbuf[r * 256 + (c4 ^ (((r >> 2) & 1) << 4))];
            *(float4*)&out[(size_t)(m0 + p * 64 + r) * N_TOT + n0 + c4] = v;
        }
    }
#undef PHASE
#undef READ_A
#undef READ_B
}

// ---------------- fallback: fused bf16 kernel (small ws) ----------------
__global__ __launch_bounds__(256, 2)
void qlin_fused(const float* __restrict__ x,
                const int* __restrict__ qw,
                const float* __restrict__ scales,
                const float* __restrict__ zeros,
                const float* __restrict__ bias,
                float* __restrict__ out) {
    __shared__ short As[128 * 64];
    __shared__ short Bs[128 * 64];

    const int tid = threadIdx.x;
    const int n0 = blockIdx.x * 128;
    const int m0 = blockIdx.y * 128;

    const int a_kg   = tid & 7;
    const int a_row0 = tid >> 3;
    const int b_oloc = tid & 127;
    const int b_rg0  = tid >> 7;

    const int ocol = n0 + b_oloc;
    const float c0 = scales[ocol];
    const float c1 = -rintf(zeros[ocol] / c0) * c0;

    const int lane = tid & 63;
    const int wv   = tid >> 6;
    const int wr   = wv >> 1;
    const int wc   = wv & 1;
    const int lrow = lane & 15;
    const int lk   = lane >> 4;

    f32x4 acc[4][4] = {};

    for (int kt = 0; kt < K_TOT / 64; ++kt) {
        const int k0 = kt * 64;
        {
            const float* srcb = x + (size_t)(m0)*K_TOT + k0 + a_kg * 8;
            #pragma unroll
            for (int i = 0; i < 4; ++i) {
                const int row = a_row0 + 32 * i;
                const float4 f0 = *(const float4*)(srcb + (size_t)row * K_TOT);
                const float4 f1 = *(const float4*)(srcb + (size_t)row * K_TOT + 4);
                s16x8 v;
                v[0] = f2bf(f0.x); v[1] = f2bf(f0.y); v[2] = f2bf(f0.z); v[3] = f2bf(f0.w);
                v[4] = f2bf(f1.x); v[5] = f2bf(f1.y); v[6] = f2bf(f1.z); v[7] = f2bf(f1.w);
                *(s16x8*)&As[row * 64 + ((a_kg ^ (row & 7)) << 3)] = v;
            }
        }
        {
            const int rbase = k0 >> 1;
            #pragma unroll
            for (int i = 0; i < 4; ++i) {
                const int rg = b_rg0 + 2 * i;
                const int* qp = qw + (size_t)(rbase + rg * 4) * N_TOT + ocol;
                s16x8 v;
                #pragma unroll
                for (int rr = 0; rr < 4; ++rr) {
                    const int q = qp[(size_t)rr * N_TOT];
                    v[2 * rr]     = f2bf(fmaf((float)(q & 15), c0, c1));
                    v[2 * rr + 1] = f2bf(fmaf((float)((q >> 4) & 15), c0, c1));
                }
                *(s16x8*)&Bs[b_oloc * 64 + ((rg ^ (b_oloc & 7)) << 3)] = v;
            }
        }
        __syncthreads();
        #pragma unroll
        for (int ks = 0; ks < 2; ++ks) {
            const int slot = ks * 4 + lk;
            s16x8 a[4], b[4];
            #pragma unroll
            for (int mi = 0; mi < 4; ++mi) {
                const int row = wr * 64 + mi * 16 + lrow;
                a[mi] = *(const s16x8*)&As[row * 64 + ((slot ^ (row & 7)) << 3)];
            }
            #pragma unroll
            for (int ni = 0; ni < 4; ++ni) {
                const int row = wc * 64 + ni * 16 + lrow;
                b[ni] = *(const s16x8*)&Bs[row * 64 + ((slot ^ (row & 7)) << 3)];
            }
            #pragma unroll
            for (int mi = 0; mi < 4; ++mi)
                #pragma unroll
                for (int ni = 0; ni < 4; ++ni)
                    acc[mi][ni] = __builtin_amdgcn_mfma_f32_16x16x32_bf16(
                        a[mi], b[ni], acc[mi][ni], 0, 0, 0);
        }
        __syncthreads();
    }

    #pragma unroll
    for (int mi = 0; mi < 4; ++mi) {
        const int rg = m0 + wr * 64 + mi * 16 + lk * 4;
        #pragma unroll
        for (int ni = 0; ni < 4; ++ni) {
            const int cg = n0 + wc * 64 + ni * 16 + lrow;
            const float bs = bias[cg];
            #pragma unroll
            for (int j = 0; j < 4; ++j)
                out[(size_t)(rg + j) * N_TOT + cg] = acc[mi][ni][j] + bs;
        }
    }
}

extern "C" void kernel_launch(void* const* d_in, const int* in_sizes, int n_in,
                              void* d_out, int out_size, void* d_ws, size_t ws_size,
                              hipStream_t stream) {
    const float* x      = (const float*)d_in[0];
    const int*   qw     = (const int*)d_in[1];
    const float* scales = (const float*)d_in[2];
    const float* zeros  = (const float*)d_in[3];
    const float* bias   = (const float*)d_in[4];
    float* out = (float*)d_out;

    const size_t XQ_BYTES = (size_t)M_TOT * K_TOT;        // 32 MiB
    const size_t WQ_BYTES = (size_t)N_TOT * K_TOT;        // 16 MiB
    const size_t SX_BYTES = (size_t)M_TOT * 4;
    const size_t NEED = XQ_BYTES + WQ_BYTES + 2 * SX_BYTES;

    if (ws_size >= NEED) {
        char*  xq   = (char*)d_ws;
        char*  wqt  = (char*)d_ws + XQ_BYTES;
        float* sxv  = (float*)((char*)d_ws + XQ_BYTES + WQ_BYTES);
        float* sumv = sxv + M_TOT;

        hipLaunchKernelGGL(prep, dim3(M_TOT + 1024), dim3(256), 0, stream,
                           x, qw, xq, wqt, sxv, sumv);
        hipLaunchKernelGGL(gemm_i8, dim3(N_TOT / BN, M_TOT / BM), dim3(512), 0, stream,
                           xq, wqt, sxv, sumv, scales, zeros, bias, out);
    } else {
        hipLaunchKernelGGL(qlin_fused, dim3(N_TOT / 128, M_TOT / 128), dim3(256), 0, stream,
                           x, qw, scales, zeros, bias, out);
    }
}